// Round 4
// baseline (152.797 us; speedup 1.0000x reference)
//
#include <hip/hip_runtime.h>
#include <hip/hip_bf16.h>
#include <math.h>

// B=32,T=512 -> NTOK=16384 tokens; F=64; H=64; E=32
#define NTOK 16384
#define PROD 65                 // producer blocks (64 ew3 slots + 1 eb3 slot)
#define CONS (NTOK / 16)        // 1024 consumer blocks, 16 tokens each

typedef __attribute__((ext_vector_type(8))) short short8;   // 8 bf16 (MFMA A/B)
typedef __attribute__((ext_vector_type(4))) float f32x4;    // MFMA acc

__device__ __forceinline__ unsigned short bf16_rne(float x) {
    unsigned int u = __float_as_uint(x);
    u += 0x7fffu + ((u >> 16) & 1u);
    return (unsigned short)(u >> 16);
}
__device__ __forceinline__ unsigned pack_bf16(float a, float b) {
    // RNE, identical results to bf16_rne pairs
    return (unsigned)bf16_rne(a) | ((unsigned)bf16_rne(b) << 16);
}
__device__ __forceinline__ float eluf(float z) {
    return z > 0.0f ? z : (__expf(z) - 1.0f);
}

// A-fragment gen: a[c] elem j = bf16(wt * elu(x*w1 + b1)), k = c*32 + quad*8 + j
__device__ __forceinline__ void gen_a(const float* __restrict__ ew1,
                                      const float* __restrict__ eb1,
                                      int f, int quad, float xv, float wt,
                                      short8* a) {
    #pragma unroll
    for (int c = 0; c < 2; ++c) {
        const float* w1p = ew1 + f * 64 + c * 32 + quad * 8;
        const float* b1p = eb1 + f * 64 + c * 32 + quad * 8;
        const float4 w1a = *(const float4*)w1p, w1b = *(const float4*)(w1p + 4);
        const float4 b1a = *(const float4*)b1p, b1b = *(const float4*)(b1p + 4);
        uint4 av;
        av.x = pack_bf16(wt * eluf(fmaf(xv, w1a.x, b1a.x)),
                         wt * eluf(fmaf(xv, w1a.y, b1a.y)));
        av.y = pack_bf16(wt * eluf(fmaf(xv, w1a.z, b1a.z)),
                         wt * eluf(fmaf(xv, w1a.w, b1a.w)));
        av.z = pack_bf16(wt * eluf(fmaf(xv, w1b.x, b1b.x)),
                         wt * eluf(fmaf(xv, w1b.y, b1b.y)));
        av.w = pack_bf16(wt * eluf(fmaf(xv, w1b.z, b1b.z)),
                         wt * eluf(fmaf(xv, w1b.w, b1b.w)));
        a[c] = *(short8*)&av;
    }
}

// fallback B-fragment gen straight from fp32 (bit-identical to image path)
__device__ __forceinline__ void gen_b_fp32(const float* __restrict__ w3f,
                                           int quad, int m, short8 b[2][4]) {
    #pragma unroll
    for (int c = 0; c < 2; ++c)
        #pragma unroll
        for (int u = 0; u < 4; ++u) {
            const float* wp = w3f + (size_t)(c * 32 + quad * 8) * 64 + u * 16 + m;
            uint4 v;
            v.x = pack_bf16(wp[0],   wp[64]);
            v.y = pack_bf16(wp[128], wp[192]);
            v.z = pack_bf16(wp[256], wp[320]);
            v.w = pack_bf16(wp[384], wp[448]);
            b[c][u] = *(short8*)&v;
        }
}

// Single kernel: blocks [0,65) build bf16 fragment-major B-images in ws and
// release per-slot flags; blocks [65, 65+1024) are 16-token consumer blocks.
__global__ __launch_bounds__(256, 4)
void moe_one(const float* __restrict__ x,   const float* __restrict__ s,
             const float* __restrict__ fw1, const float* __restrict__ fb1,
             const float* __restrict__ fw2, const float* __restrict__ fb2,
             const float* __restrict__ fw3, const float* __restrict__ fb3,
             const float* __restrict__ ew1, const float* __restrict__ eb1,
             const float* __restrict__ ew3, const float* __restrict__ eb3,
             unsigned short* __restrict__ w3img, int use_ws,
             float* __restrict__ out)
{
    __shared__ __align__(16) char smem[30016];
    const int tid = threadIdx.x;
    const int bid = blockIdx.x;
    int* flags = (int*)(w3img + (size_t)PROD * 4096);

    // ================= producer blocks =================
    if (bid < PROD) {
        if (!use_ws) return;
        float* tile = (float*)smem;                       // 64*65 fp32 = 16.6 KB
        const float* src = (bid < 64) ? (ew3 + (size_t)bid * 4096) : eb3;
        const int r = tid >> 2, c0 = (tid & 3) * 16;
        #pragma unroll
        for (int j = 0; j < 4; ++j) {
            float4 v = *(const float4*)(src + r * 64 + c0 + j * 4);
            tile[r * 65 + c0 + j * 4 + 0] = v.x;
            tile[r * 65 + c0 + j * 4 + 1] = v.y;
            tile[r * 65 + c0 + j * 4 + 2] = v.z;
            tile[r * 65 + c0 + j * 4 + 3] = v.w;
        }
        __syncthreads();
        uint4* dst = (uint4*)(w3img + (size_t)bid * 4096);
        #pragma unroll
        for (int it = 0; it < 2; ++it) {
            const int idx = tid + it * 256;
            const int c = idx >> 8, u = (idx >> 6) & 3, l = idx & 63;
            const int m = l & 15, q = (l >> 4) & 3;
            const int rb = c * 32 + q * 8, col = u * 16 + m;
            unsigned pw[4];
            #pragma unroll
            for (int p = 0; p < 4; ++p)
                pw[p] = pack_bf16(tile[(rb + 2 * p) * 65 + col],
                                  tile[(rb + 2 * p + 1) * 65 + col]);
            uint4 pk; pk.x = pw[0]; pk.y = pw[1]; pk.z = pw[2]; pk.w = pw[3];
            dst[idx] = pk;
        }
        __syncthreads();   // barrier drains vmcnt -> all image stores issued/complete
        if (tid == 0)
            __hip_atomic_store(&flags[bid], 1, __ATOMIC_RELEASE,
                               __HIP_MEMORY_SCOPE_AGENT);
        return;
    }

    // ================= consumer blocks =================
    float* xls = (float*)smem;                 // [16][68] x tile      (4352 B)
    float* wts = (float*)(smem + 4352);        // [16][65] gates       (4160 B)
    float* egs = (float*)(smem + 8512);        // [4][4][64] elu(g)    (4096 B)
    float* ped = (float*)(smem + 12608);       // [4][16][68] partials (17408 B)

    const int wv = tid >> 6, lane = tid & 63;
    const int tokbase = (bid - PROD) * 16;

    // ---- stage x tile ----
    {
        const int t = tid >> 4, fq = (tid & 15) * 4;
        float4 v = *(const float4*)(x + (size_t)(tokbase + t) * 64 + fq);
        *(float4*)&xls[t * 68 + fq] = v;
    }
    __syncthreads();

    // ---- gating: wave computes softmax gate for its 4 tokens ----
    {
        const int t0w = wv * 4;
        const float* sw = s + (size_t)(tokbase + t0w) * 32;
        float g[4];
        const float b0 = fb1[lane] + fb2[lane];
        #pragma unroll
        for (int t = 0; t < 4; ++t) g[t] = b0;
        for (int f = 0; f < 64; ++f) {
            const float w = fw1[f * 64 + lane];
            #pragma unroll
            for (int t = 0; t < 4; ++t)
                g[t] = fmaf(xls[(t0w + t) * 68 + f], w, g[t]);
        }
        for (int e = 0; e < 32; ++e) {
            const float w = fw2[e * 64 + lane];
            #pragma unroll
            for (int t = 0; t < 4; ++t) g[t] = fmaf(sw[t * 32 + e], w, g[t]);
        }
        #pragma unroll
        for (int t = 0; t < 4; ++t) egs[wv * 256 + t * 64 + lane] = eluf(g[t]);

        float lg[4];
        const float b3 = fb3[lane];
        #pragma unroll
        for (int t = 0; t < 4; ++t) lg[t] = b3;
        for (int hq = 0; hq < 16; ++hq) {
            const float4 e0 = *(const float4*)&egs[wv * 256 + 0 * 64 + hq * 4];
            const float4 e1 = *(const float4*)&egs[wv * 256 + 1 * 64 + hq * 4];
            const float4 e2 = *(const float4*)&egs[wv * 256 + 2 * 64 + hq * 4];
            const float4 e3 = *(const float4*)&egs[wv * 256 + 3 * 64 + hq * 4];
            const float w0 = fw3[(hq * 4 + 0) * 64 + lane];
            const float w1 = fw3[(hq * 4 + 1) * 64 + lane];
            const float w2 = fw3[(hq * 4 + 2) * 64 + lane];
            const float w3v = fw3[(hq * 4 + 3) * 64 + lane];
            lg[0] = fmaf(e0.x, w0, fmaf(e0.y, w1, fmaf(e0.z, w2, fmaf(e0.w, w3v, lg[0]))));
            lg[1] = fmaf(e1.x, w0, fmaf(e1.y, w1, fmaf(e1.z, w2, fmaf(e1.w, w3v, lg[1]))));
            lg[2] = fmaf(e2.x, w0, fmaf(e2.y, w1, fmaf(e2.z, w2, fmaf(e2.w, w3v, lg[2]))));
            lg[3] = fmaf(e3.x, w0, fmaf(e3.y, w1, fmaf(e3.z, w2, fmaf(e3.w, w3v, lg[3]))));
        }
        #pragma unroll
        for (int t = 0; t < 4; ++t) {
            float mx = lg[t];
            #pragma unroll
            for (int off = 32; off > 0; off >>= 1) mx = fmaxf(mx, __shfl_xor(mx, off));
            const float p = __expf(lg[t] - mx);
            float sm = p;
            #pragma unroll
            for (int off = 32; off > 0; off >>= 1) sm += __shfl_xor(sm, off);
            wts[(t0w + t) * 65 + lane] = p / sm;
        }
    }
    __syncthreads();

    // ---- resolve producer flags (bounded spin; fallback = fp32 direct) ----
    const int m = tid & 15, quad = (tid >> 4) & 3;
    const int f0 = wv * 16;
    bool ok = false;
    if (use_ws) {
        const int fidx = (lane < 16) ? (f0 + lane) : 64;
        for (int spin = 0; spin < 256 && !ok; ++spin) {
            int v = 1;
            if (lane <= 16)
                v = __hip_atomic_load(&flags[fidx], __ATOMIC_RELAXED,
                                      __HIP_MEMORY_SCOPE_AGENT);
            ok = (__ballot(v == 1) == ~0ull);
            if (!ok) __builtin_amdgcn_s_sleep(1);
        }
        if (ok) __builtin_amdgcn_fence(__ATOMIC_ACQUIRE, "agent");
    }

    f32x4 acc[4];
    #pragma unroll
    for (int u = 0; u < 4; ++u) acc[u] = (f32x4){0.f, 0.f, 0.f, 0.f};

    if (ok) {
        // ---- software-pipelined K-loop over this wave's 16 features ----
        const uint4* bb = (const uint4*)w3img;
        uint4 bn[8];
        #pragma unroll
        for (int i = 0; i < 8; ++i)
            bn[i] = bb[(size_t)f0 * 512 + (i >> 2) * 256 + (i & 3) * 64 + lane];
        float xnv = xls[m * 68 + f0];
        float wnv = wts[m * 65 + f0];
        #pragma unroll
        for (int ff = 0; ff < 16; ++ff) {
            uint4 bc[8];
            #pragma unroll
            for (int i = 0; i < 8; ++i) bc[i] = bn[i];
            const float xv = xnv, wt = wnv;
            if (ff < 15) {
                #pragma unroll
                for (int i = 0; i < 8; ++i)
                    bn[i] = bb[(size_t)(f0 + ff + 1) * 512 + (i >> 2) * 256 + (i & 3) * 64 + lane];
                xnv = xls[m * 68 + f0 + ff + 1];
                wnv = wts[m * 65 + f0 + ff + 1];
            }
            short8 a[2];
            gen_a(ew1, eb1, f0 + ff, quad, xv, wt, a);
            #pragma unroll
            for (int u = 0; u < 4; ++u) {
                acc[u] = __builtin_amdgcn_mfma_f32_16x16x32_bf16(a[0], *(short8*)&bc[u],     acc[u], 0, 0, 0);
                acc[u] = __builtin_amdgcn_mfma_f32_16x16x32_bf16(a[1], *(short8*)&bc[4 + u], acc[u], 0, 0, 0);
            }
        }
    } else {
        // ---- fallback: pack B from fp32 in-loop (bit-identical values) ----
        for (int ff = 0; ff < 16; ++ff) {
            const int f = f0 + ff;
            short8 b[2][4];
            gen_b_fp32(ew3 + (size_t)f * 4096, quad, m, b);
            short8 a[2];
            gen_a(ew1, eb1, f, quad, xls[m * 68 + f], wts[m * 65 + f], a);
            #pragma unroll
            for (int u = 0; u < 4; ++u) {
                acc[u] = __builtin_amdgcn_mfma_f32_16x16x32_bf16(a[0], b[0][u], acc[u], 0, 0, 0);
                acc[u] = __builtin_amdgcn_mfma_f32_16x16x32_bf16(a[1], b[1][u], acc[u], 0, 0, 0);
            }
        }
    }

    // ---- bias K-chunk: out += w_t @ eb3 ; wave 0 -> e 0..31, wave 1 -> e 32..63 ----
    if (wv < 2) {
        const int e0 = wv * 32 + quad * 8;
        uint4 av;
        av.x = pack_bf16(wts[m * 65 + e0 + 0], wts[m * 65 + e0 + 1]);
        av.y = pack_bf16(wts[m * 65 + e0 + 2], wts[m * 65 + e0 + 3]);
        av.z = pack_bf16(wts[m * 65 + e0 + 4], wts[m * 65 + e0 + 5]);
        av.w = pack_bf16(wts[m * 65 + e0 + 6], wts[m * 65 + e0 + 7]);
        short8 a = *(short8*)&av;
        short8 b[4];
        if (ok) {
            const uint4* bp = (const uint4*)(w3img + (size_t)64 * 4096);
            #pragma unroll
            for (int u = 0; u < 4; ++u) {
                uint4 bv = bp[wv * 256 + u * 64 + lane];
                b[u] = *(short8*)&bv;
            }
        } else {
            #pragma unroll
            for (int u = 0; u < 4; ++u) {
                const float* wp = eb3 + (size_t)(wv * 32 + quad * 8) * 64 + u * 16 + m;
                uint4 bv;
                bv.x = pack_bf16(wp[0],   wp[64]);
                bv.y = pack_bf16(wp[128], wp[192]);
                bv.z = pack_bf16(wp[256], wp[320]);
                bv.w = pack_bf16(wp[384], wp[448]);
                b[u] = *(short8*)&bv;
            }
        }
        #pragma unroll
        for (int u = 0; u < 4; ++u)
            acc[u] = __builtin_amdgcn_mfma_f32_16x16x32_bf16(a, b[u], acc[u], 0, 0, 0);
    }

    // ---- K-split reduction through LDS (C layout: col=lane&15, row=quad*4+r) ----
    #pragma unroll
    for (int u = 0; u < 4; ++u)
        #pragma unroll
        for (int r = 0; r < 4; ++r)
            ped[wv * 1088 + (quad * 4 + r) * 68 + u * 16 + m] = acc[u][r];
    __syncthreads();

    const int t = tid >> 4, kq = tid & 15;
    const float4 p0 = *(const float4*)&ped[0 * 1088 + t * 68 + kq * 4];
    const float4 p1 = *(const float4*)&ped[1 * 1088 + t * 68 + kq * 4];
    const float4 p2 = *(const float4*)&ped[2 * 1088 + t * 68 + kq * 4];
    const float4 p3 = *(const float4*)&ped[3 * 1088 + t * 68 + kq * 4];
    float4 o;
    o.x = (p0.x + p1.x) + (p2.x + p3.x);
    o.y = (p0.y + p1.y) + (p2.y + p3.y);
    o.z = (p0.z + p1.z) + (p2.z + p3.z);
    o.w = (p0.w + p1.w) + (p2.w + p3.w);
    *(float4*)(out + (size_t)(tokbase + t) * 64 + kq * 4) = o;
}

extern "C" void kernel_launch(void* const* d_in, const int* in_sizes, int n_in,
                              void* d_out, int out_size, void* d_ws, size_t ws_size,
                              hipStream_t stream) {
    const float* x   = (const float*)d_in[0];
    const float* s   = (const float*)d_in[1];
    const float* fw1 = (const float*)d_in[2];
    const float* fb1 = (const float*)d_in[3];
    const float* fw2 = (const float*)d_in[4];
    const float* fb2 = (const float*)d_in[5];
    const float* fw3 = (const float*)d_in[6];
    const float* fb3 = (const float*)d_in[7];
    const float* ew1 = (const float*)d_in[8];
    const float* eb1 = (const float*)d_in[9];
    const float* ew3 = (const float*)d_in[10];
    const float* eb3 = (const float*)d_in[11];
    float* out = (float*)d_out;

    // 65 image slots (bf16) + 65 flag ints
    const size_t ws_need = (size_t)PROD * 4096 * sizeof(unsigned short) + PROD * sizeof(int);
    const int use_ws = (ws_size >= ws_need) && (((uintptr_t)d_ws & 15) == 0);
    unsigned short* w3img = (unsigned short*)d_ws;

    moe_one<<<dim3(PROD + CONS), dim3(256), 0, stream>>>(
        x, s, fw1, fb1, fw2, fb2, fw3, fb3, ew1, eb1, ew3, eb3,
        w3img, use_ws, out);
}

// Round 5
// 130.205 us; speedup vs baseline: 1.1735x; 1.1735x over previous
//
#include <hip/hip_runtime.h>
#include <hip/hip_bf16.h>
#include <math.h>

// B=32,T=512 -> NTOK=16384 tokens; F=64; H=64; E=32
#define NTOK 16384

typedef __attribute__((ext_vector_type(8))) short short8;   // 8 bf16 (MFMA A/B)
typedef __attribute__((ext_vector_type(4))) float f32x4;    // MFMA acc

__device__ __forceinline__ unsigned pack_bf16(float a, float b) {
    // hw v_cvt_pk_bf16_f32 (RNE)
    union { __hip_bfloat162 h; unsigned u; } cv;
    cv.h = __float22bfloat162_rn(make_float2(a, b));
    return cv.u;
}
__device__ __forceinline__ float eluf(float z) {
    return z > 0.0f ? z : (__expf(z) - 1.0f);
}

// ---------------- prepass: fragment-major bf16 B images ----------------
// slot f (0..63): B = ew3[f] (rows k=h, cols n); slot 64: B = eb3 (rows e, cols n)
// image[f][idx] uint4, idx = c*256 + u*64 + lane:
//   elem j of lane's short8 = B[c*32 + (lane>>4)*8 + j][u*16 + (lane&15)]
__global__ __launch_bounds__(256)
void prepass(const float* __restrict__ ew3, const float* __restrict__ eb3,
             unsigned short* __restrict__ ws) {
    __shared__ float tile[64 * 65];
    const int bid = blockIdx.x, tid = threadIdx.x;
    const float* src = (bid < 64) ? (ew3 + (size_t)bid * 4096) : eb3;

    const int r = tid >> 2, c0 = (tid & 3) * 16;
    #pragma unroll
    for (int j = 0; j < 4; ++j) {
        float4 v = *(const float4*)(src + r * 64 + c0 + j * 4);
        tile[r * 65 + c0 + j * 4 + 0] = v.x;
        tile[r * 65 + c0 + j * 4 + 1] = v.y;
        tile[r * 65 + c0 + j * 4 + 2] = v.z;
        tile[r * 65 + c0 + j * 4 + 3] = v.w;
    }
    __syncthreads();

    uint4* dst = (uint4*)(ws + (size_t)bid * 4096);
    #pragma unroll
    for (int it = 0; it < 2; ++it) {
        const int idx = tid + it * 256;
        const int c = idx >> 8, u = (idx >> 6) & 3, l = idx & 63;
        const int m = l & 15, q = (l >> 4) & 3;
        const int rb = c * 32 + q * 8, col = u * 16 + m;
        unsigned pw[4];
        #pragma unroll
        for (int p = 0; p < 4; ++p)
            pw[p] = pack_bf16(tile[(rb + 2 * p) * 65 + col],
                              tile[(rb + 2 * p + 1) * 65 + col]);
        uint4 pk; pk.x = pw[0]; pk.y = pw[1]; pk.z = pw[2]; pk.w = pw[3];
        dst[idx] = pk;
    }
}

// A-fragment gen: a[c] elem j = bf16(wt * elu(x*w1 + b1)), k = c*32 + quad*8 + j
__device__ __forceinline__ void gen_a(const float* __restrict__ ew1,
                                      const float* __restrict__ eb1,
                                      int f, int quad, float xv, float wt,
                                      short8* a) {
    #pragma unroll
    for (int c = 0; c < 2; ++c) {
        const float* w1p = ew1 + f * 64 + c * 32 + quad * 8;
        const float* b1p = eb1 + f * 64 + c * 32 + quad * 8;
        const float4 w1a = *(const float4*)w1p, w1b = *(const float4*)(w1p + 4);
        const float4 b1a = *(const float4*)b1p, b1b = *(const float4*)(b1p + 4);
        uint4 av;
        av.x = pack_bf16(wt * eluf(fmaf(xv, w1a.x, b1a.x)),
                         wt * eluf(fmaf(xv, w1a.y, b1a.y)));
        av.y = pack_bf16(wt * eluf(fmaf(xv, w1a.z, b1a.z)),
                         wt * eluf(fmaf(xv, w1a.w, b1a.w)));
        av.z = pack_bf16(wt * eluf(fmaf(xv, w1b.x, b1b.x)),
                         wt * eluf(fmaf(xv, w1b.y, b1b.y)));
        av.w = pack_bf16(wt * eluf(fmaf(xv, w1b.z, b1b.z)),
                         wt * eluf(fmaf(xv, w1b.w, b1b.w)));
        a[c] = *(short8*)&av;
    }
}

// fallback B-fragment gen straight from fp32 (bit-identical values)
__device__ __forceinline__ void gen_b_fp32(const float* __restrict__ w3f,
                                           int quad, int m, short8 b[2][4]) {
    #pragma unroll
    for (int c = 0; c < 2; ++c)
        #pragma unroll
        for (int u = 0; u < 4; ++u) {
            const float* wp = w3f + (size_t)(c * 32 + quad * 8) * 64 + u * 16 + m;
            uint4 v;
            v.x = pack_bf16(wp[0],   wp[64]);
            v.y = pack_bf16(wp[128], wp[192]);
            v.z = pack_bf16(wp[256], wp[320]);
            v.w = pack_bf16(wp[384], wp[448]);
            b[c][u] = *(short8*)&v;
        }
}

// ---------------- main kernel: 1024 blocks x 512 thr (8 waves) ----------------
// block = 16 tokens; wave w owns f in [w*8, w*8+8)  (8-way K-split)
// -> 32 waves/CU (8/SIMD), zero barriers in the f-loop.
__global__ __launch_bounds__(512, 8)
void moe_main(const float* __restrict__ x,   const float* __restrict__ s,
              const float* __restrict__ fw1, const float* __restrict__ fb1,
              const float* __restrict__ fw2, const float* __restrict__ fb2,
              const float* __restrict__ fw3, const float* __restrict__ fb3,
              const float* __restrict__ ew1, const float* __restrict__ eb1,
              const float* __restrict__ ew3, const float* __restrict__ eb3,
              const unsigned short* __restrict__ w3img, int use_ws,
              float* __restrict__ out)
{
    __shared__ __align__(16) float xls[16 * 68];    // x tile [t][f]       4352 B
    __shared__ __align__(16) float wts[16 * 65];    // gates  [t][f]       4160 B
    __shared__ __align__(16) float egs[16 * 64];    // elu(g) [t][h]       4096 B
    __shared__ __align__(16) float ped[4][16 * 68]; // partials (tree)    17408 B

    const int tid = threadIdx.x;
    const int wv = tid >> 6, lane = tid & 63;
    const int tokbase = blockIdx.x * 16;

    // ---- stage x tile (first 256 threads) ----
    if (tid < 256) {
        const int t = tid >> 4, fq = (tid & 15) * 4;
        *(float4*)&xls[t * 68 + fq] =
            *(const float4*)(x + (size_t)(tokbase + t) * 64 + fq);
    }
    __syncthreads();

    // ---- gating: each wave computes softmax gates for its 2 tokens ----
    {
        const int t0w = wv * 2;
        const float* sw = s + (size_t)(tokbase + t0w) * 32;
        float g0, g1;
        g0 = g1 = fb1[lane] + fb2[lane];
        for (int f = 0; f < 64; f += 4) {
            const float4 xa = *(const float4*)&xls[(t0w + 0) * 68 + f];
            const float4 xb = *(const float4*)&xls[(t0w + 1) * 68 + f];
            const float w0 = fw1[(f + 0) * 64 + lane];
            const float w1 = fw1[(f + 1) * 64 + lane];
            const float w2 = fw1[(f + 2) * 64 + lane];
            const float w3v = fw1[(f + 3) * 64 + lane];
            g0 = fmaf(xa.x, w0, fmaf(xa.y, w1, fmaf(xa.z, w2, fmaf(xa.w, w3v, g0))));
            g1 = fmaf(xb.x, w0, fmaf(xb.y, w1, fmaf(xb.z, w2, fmaf(xb.w, w3v, g1))));
        }
        for (int e = 0; e < 32; e += 4) {
            const float4 sa = *(const float4*)(sw + e);
            const float4 sb = *(const float4*)(sw + 32 + e);
            const float w0 = fw2[(e + 0) * 64 + lane];
            const float w1 = fw2[(e + 1) * 64 + lane];
            const float w2 = fw2[(e + 2) * 64 + lane];
            const float w3v = fw2[(e + 3) * 64 + lane];
            g0 = fmaf(sa.x, w0, fmaf(sa.y, w1, fmaf(sa.z, w2, fmaf(sa.w, w3v, g0))));
            g1 = fmaf(sb.x, w0, fmaf(sb.y, w1, fmaf(sb.z, w2, fmaf(sb.w, w3v, g1))));
        }
        egs[(t0w + 0) * 64 + lane] = eluf(g0);
        egs[(t0w + 1) * 64 + lane] = eluf(g1);
        __syncthreads();   // (wave-local would suffice; cheap and safe)

        float lg0 = fb3[lane], lg1 = lg0;
        for (int h = 0; h < 64; h += 4) {
            const float4 e0 = *(const float4*)&egs[(t0w + 0) * 64 + h];
            const float4 e1 = *(const float4*)&egs[(t0w + 1) * 64 + h];
            const float w0 = fw3[(h + 0) * 64 + lane];
            const float w1 = fw3[(h + 1) * 64 + lane];
            const float w2 = fw3[(h + 2) * 64 + lane];
            const float w3v = fw3[(h + 3) * 64 + lane];
            lg0 = fmaf(e0.x, w0, fmaf(e0.y, w1, fmaf(e0.z, w2, fmaf(e0.w, w3v, lg0))));
            lg1 = fmaf(e1.x, w0, fmaf(e1.y, w1, fmaf(e1.z, w2, fmaf(e1.w, w3v, lg1))));
        }
        float mx0 = lg0, mx1 = lg1;
        #pragma unroll
        for (int off = 32; off > 0; off >>= 1) {
            mx0 = fmaxf(mx0, __shfl_xor(mx0, off));
            mx1 = fmaxf(mx1, __shfl_xor(mx1, off));
        }
        const float p0 = __expf(lg0 - mx0), p1 = __expf(lg1 - mx1);
        float s0 = p0, s1 = p1;
        #pragma unroll
        for (int off = 32; off > 0; off >>= 1) {
            s0 += __shfl_xor(s0, off);
            s1 += __shfl_xor(s1, off);
        }
        wts[(t0w + 0) * 65 + lane] = p0 / s0;
        wts[(t0w + 1) * 65 + lane] = p1 / s1;
    }
    __syncthreads();

    // ---- MFMA main loop: wave tile = 16 tok x 64 out, f in [wv*8, wv*8+8) ----
    const int m = tid & 15, quad = (tid >> 4) & 3;
    const int f0 = wv * 8;

    f32x4 acc[4];
    #pragma unroll
    for (int u = 0; u < 4; ++u) acc[u] = (f32x4){0.f, 0.f, 0.f, 0.f};

    if (use_ws) {
        const uint4* bb = (const uint4*)w3img;
        #pragma unroll
        for (int ff = 0; ff < 8; ++ff) {
            const int f = f0 + ff;
            const uint4* bp = bb + (size_t)f * 512;
            const float xv = xls[m * 68 + f];
            const float wt = wts[m * 65 + f];
            short8 a[2];
            gen_a(ew1, eb1, f, quad, xv, wt, a);
            // chunk c=0
            {
                uint4 b0 = bp[0 * 256 + 0 * 64 + lane];
                uint4 b1 = bp[0 * 256 + 1 * 64 + lane];
                uint4 b2 = bp[0 * 256 + 2 * 64 + lane];
                uint4 b3 = bp[0 * 256 + 3 * 64 + lane];
                acc[0] = __builtin_amdgcn_mfma_f32_16x16x32_bf16(a[0], *(short8*)&b0, acc[0], 0, 0, 0);
                acc[1] = __builtin_amdgcn_mfma_f32_16x16x32_bf16(a[0], *(short8*)&b1, acc[1], 0, 0, 0);
                acc[2] = __builtin_amdgcn_mfma_f32_16x16x32_bf16(a[0], *(short8*)&b2, acc[2], 0, 0, 0);
                acc[3] = __builtin_amdgcn_mfma_f32_16x16x32_bf16(a[0], *(short8*)&b3, acc[3], 0, 0, 0);
            }
            // chunk c=1
            {
                uint4 b0 = bp[1 * 256 + 0 * 64 + lane];
                uint4 b1 = bp[1 * 256 + 1 * 64 + lane];
                uint4 b2 = bp[1 * 256 + 2 * 64 + lane];
                uint4 b3 = bp[1 * 256 + 3 * 64 + lane];
                acc[0] = __builtin_amdgcn_mfma_f32_16x16x32_bf16(a[1], *(short8*)&b0, acc[0], 0, 0, 0);
                acc[1] = __builtin_amdgcn_mfma_f32_16x16x32_bf16(a[1], *(short8*)&b1, acc[1], 0, 0, 0);
                acc[2] = __builtin_amdgcn_mfma_f32_16x16x32_bf16(a[1], *(short8*)&b2, acc[2], 0, 0, 0);
                acc[3] = __builtin_amdgcn_mfma_f32_16x16x32_bf16(a[1], *(short8*)&b3, acc[3], 0, 0, 0);
            }
        }
    } else {
        for (int ff = 0; ff < 8; ++ff) {
            const int f = f0 + ff;
            short8 b[2][4], a[2];
            gen_b_fp32(ew3 + (size_t)f * 4096, quad, m, b);
            gen_a(ew1, eb1, f, quad, xls[m * 68 + f], wts[m * 65 + f], a);
            #pragma unroll
            for (int u = 0; u < 4; ++u) {
                acc[u] = __builtin_amdgcn_mfma_f32_16x16x32_bf16(a[0], b[0][u], acc[u], 0, 0, 0);
                acc[u] = __builtin_amdgcn_mfma_f32_16x16x32_bf16(a[1], b[1][u], acc[u], 0, 0, 0);
            }
        }
    }

    // ---- bias K-chunk (waves 0,1): out += w_t @ eb3 ----
    if (wv < 2) {
        const int e0 = wv * 32 + quad * 8;
        uint4 av;
        av.x = pack_bf16(wts[m * 65 + e0 + 0], wts[m * 65 + e0 + 1]);
        av.y = pack_bf16(wts[m * 65 + e0 + 2], wts[m * 65 + e0 + 3]);
        av.z = pack_bf16(wts[m * 65 + e0 + 4], wts[m * 65 + e0 + 5]);
        av.w = pack_bf16(wts[m * 65 + e0 + 6], wts[m * 65 + e0 + 7]);
        short8 a = *(short8*)&av;
        short8 b[4];
        if (use_ws) {
            const uint4* bp = (const uint4*)(w3img + (size_t)64 * 4096);
            #pragma unroll
            for (int u = 0; u < 4; ++u) {
                uint4 bv = bp[wv * 256 + u * 64 + lane];
                b[u] = *(short8*)&bv;
            }
        } else {
            #pragma unroll
            for (int u = 0; u < 4; ++u) {
                const float* wp = eb3 + (size_t)e0 * 64 + u * 16 + m;
                uint4 bv;
                bv.x = pack_bf16(wp[0],   wp[64]);
                bv.y = pack_bf16(wp[128], wp[192]);
                bv.z = pack_bf16(wp[256], wp[320]);
                bv.w = pack_bf16(wp[384], wp[448]);
                b[u] = *(short8*)&bv;
            }
        }
        #pragma unroll
        for (int u = 0; u < 4; ++u)
            acc[u] = __builtin_amdgcn_mfma_f32_16x16x32_bf16(a, b[u], acc[u], 0, 0, 0);
    }

    // ---- tree reduction over 8 wave-partials (C layout: row=quad*4+r, col=u*16+m) ----
    // round 1: waves 4..7 -> ped[0..3]; waves 0..3 add
    if (wv >= 4) {
        #pragma unroll
        for (int u = 0; u < 4; ++u)
            #pragma unroll
            for (int r = 0; r < 4; ++r)
                ped[wv - 4][(quad * 4 + r) * 68 + u * 16 + m] = acc[u][r];
    }
    __syncthreads();
    if (wv < 4) {
        #pragma unroll
        for (int u = 0; u < 4; ++u)
            #pragma unroll
            for (int r = 0; r < 4; ++r)
                acc[u][r] += ped[wv][(quad * 4 + r) * 68 + u * 16 + m];
    }
    __syncthreads();
    // round 2: waves 2,3 -> ped[0,1]; waves 0,1 add
    if (wv == 2 || wv == 3) {
        #pragma unroll
        for (int u = 0; u < 4; ++u)
            #pragma unroll
            for (int r = 0; r < 4; ++r)
                ped[wv - 2][(quad * 4 + r) * 68 + u * 16 + m] = acc[u][r];
    }
    __syncthreads();
    if (wv < 2) {
        #pragma unroll
        for (int u = 0; u < 4; ++u)
            #pragma unroll
            for (int r = 0; r < 4; ++r)
                acc[u][r] += ped[wv][(quad * 4 + r) * 68 + u * 16 + m];
    }
    __syncthreads();
    // round 3: wave 1 -> ped[0]; wave 0 adds, writes final into ped[0]
    if (wv == 1) {
        #pragma unroll
        for (int u = 0; u < 4; ++u)
            #pragma unroll
            for (int r = 0; r < 4; ++r)
                ped[0][(quad * 4 + r) * 68 + u * 16 + m] = acc[u][r];
    }
    __syncthreads();
    if (wv == 0) {
        #pragma unroll
        for (int u = 0; u < 4; ++u)
            #pragma unroll
            for (int r = 0; r < 4; ++r) {
                const int idx = (quad * 4 + r) * 68 + u * 16 + m;
                ped[0][idx] += acc[u][r];
            }
    }
    __syncthreads();

    // ---- final store: [t][k] fp32, float4, coalesced ----
    if (tid < 256) {
        const int t = tid >> 4, kq = tid & 15;
        float4 o = *(const float4*)&ped[0][t * 68 + kq * 4];
        *(float4*)(out + (size_t)(tokbase + t) * 64 + kq * 4) = o;
    }
}

extern "C" void kernel_launch(void* const* d_in, const int* in_sizes, int n_in,
                              void* d_out, int out_size, void* d_ws, size_t ws_size,
                              hipStream_t stream) {
    const float* x   = (const float*)d_in[0];
    const float* s   = (const float*)d_in[1];
    const float* fw1 = (const float*)d_in[2];
    const float* fb1 = (const float*)d_in[3];
    const float* fw2 = (const float*)d_in[4];
    const float* fb2 = (const float*)d_in[5];
    const float* fw3 = (const float*)d_in[6];
    const float* fb3 = (const float*)d_in[7];
    const float* ew1 = (const float*)d_in[8];
    const float* eb1 = (const float*)d_in[9];
    const float* ew3 = (const float*)d_in[10];
    const float* eb3 = (const float*)d_in[11];
    float* out = (float*)d_out;

    const size_t ws_need = (size_t)65 * 4096 * sizeof(unsigned short);  // 532,480 B
    const int use_ws = (ws_size >= ws_need) && (((uintptr_t)d_ws & 15) == 0);
    unsigned short* w3img = (unsigned short*)d_ws;

    if (use_ws) prepass<<<dim3(65), dim3(256), 0, stream>>>(ew3, eb3, w3img);
    moe_main<<<dim3(NTOK / 16), dim3(512), 0, stream>>>(
        x, s, fw1, fb1, fw2, fb2, fw3, fb3, ew1, eb1, ew3, eb3,
        w3img, use_ws, out);
}

// Round 6
// 125.926 us; speedup vs baseline: 1.2134x; 1.0340x over previous
//
#include <hip/hip_runtime.h>
#include <hip/hip_bf16.h>
#include <math.h>

// B=32,T=512 -> NTOK=16384 tokens; F=64; H=64; E=32
#define NTOK 16384

typedef __attribute__((ext_vector_type(8))) short short8;   // 8 bf16 (MFMA A/B)
typedef __attribute__((ext_vector_type(4))) float f32x4;    // MFMA acc

__device__ __forceinline__ unsigned pack_bf16(float a, float b) {
    // hw v_cvt_pk_bf16_f32 (RNE)
    union { __hip_bfloat162 h; unsigned u; } cv;
    cv.h = __float22bfloat162_rn(make_float2(a, b));
    return cv.u;
}
__device__ __forceinline__ float eluf(float z) {
    return z > 0.0f ? z : (__expf(z) - 1.0f);
}

// ---------------- prepass: fragment-major bf16 B images ----------------
// slot f (0..63): B = ew3[f] (rows k=h, cols n); slot 64: B = eb3 (rows e, cols n)
// image[f][idx] uint4, idx = c*256 + u*64 + lane:
//   elem j of lane's short8 = B[c*32 + (lane>>4)*8 + j][u*16 + (lane&15)]
__global__ __launch_bounds__(256)
void prepass(const float* __restrict__ ew3, const float* __restrict__ eb3,
             unsigned short* __restrict__ ws) {
    __shared__ float tile[64 * 65];
    const int bid = blockIdx.x, tid = threadIdx.x;
    const float* src = (bid < 64) ? (ew3 + (size_t)bid * 4096) : eb3;

    const int r = tid >> 2, c0 = (tid & 3) * 16;
    #pragma unroll
    for (int j = 0; j < 4; ++j) {
        float4 v = *(const float4*)(src + r * 64 + c0 + j * 4);
        tile[r * 65 + c0 + j * 4 + 0] = v.x;
        tile[r * 65 + c0 + j * 4 + 1] = v.y;
        tile[r * 65 + c0 + j * 4 + 2] = v.z;
        tile[r * 65 + c0 + j * 4 + 3] = v.w;
    }
    __syncthreads();

    uint4* dst = (uint4*)(ws + (size_t)bid * 4096);
    #pragma unroll
    for (int it = 0; it < 2; ++it) {
        const int idx = tid + it * 256;
        const int c = idx >> 8, u = (idx >> 6) & 3, l = idx & 63;
        const int m = l & 15, q = (l >> 4) & 3;
        const int rb = c * 32 + q * 8, col = u * 16 + m;
        unsigned pw[4];
        #pragma unroll
        for (int p = 0; p < 4; ++p)
            pw[p] = pack_bf16(tile[(rb + 2 * p) * 65 + col],
                              tile[(rb + 2 * p + 1) * 65 + col]);
        uint4 pk; pk.x = pw[0]; pk.y = pw[1]; pk.z = pw[2]; pk.w = pw[3];
        dst[idx] = pk;
    }
}

// A-fragment gen: a[c] elem j = bf16(wt * elu(x*w1 + b1)), k = c*32 + quad*8 + j
__device__ __forceinline__ void gen_a(const float* __restrict__ ew1,
                                      const float* __restrict__ eb1,
                                      int f, int quad, float xv, float wt,
                                      short8* a) {
    #pragma unroll
    for (int c = 0; c < 2; ++c) {
        const float* w1p = ew1 + f * 64 + c * 32 + quad * 8;
        const float* b1p = eb1 + f * 64 + c * 32 + quad * 8;
        const float4 w1a = *(const float4*)w1p, w1b = *(const float4*)(w1p + 4);
        const float4 b1a = *(const float4*)b1p, b1b = *(const float4*)(b1p + 4);
        uint4 av;
        av.x = pack_bf16(wt * eluf(fmaf(xv, w1a.x, b1a.x)),
                         wt * eluf(fmaf(xv, w1a.y, b1a.y)));
        av.y = pack_bf16(wt * eluf(fmaf(xv, w1a.z, b1a.z)),
                         wt * eluf(fmaf(xv, w1a.w, b1a.w)));
        av.z = pack_bf16(wt * eluf(fmaf(xv, w1b.x, b1b.x)),
                         wt * eluf(fmaf(xv, w1b.y, b1b.y)));
        av.w = pack_bf16(wt * eluf(fmaf(xv, w1b.z, b1b.z)),
                         wt * eluf(fmaf(xv, w1b.w, b1b.w)));
        a[c] = *(short8*)&av;
    }
}

// fallback B-fragment gen straight from fp32 (bit-identical values)
__device__ __forceinline__ void gen_b_fp32(const float* __restrict__ w3f,
                                           int quad, int m, short8 b[2][4]) {
    #pragma unroll
    for (int c = 0; c < 2; ++c)
        #pragma unroll
        for (int u = 0; u < 4; ++u) {
            const float* wp = w3f + (size_t)(c * 32 + quad * 8) * 64 + u * 16 + m;
            uint4 v;
            v.x = pack_bf16(wp[0],   wp[64]);
            v.y = pack_bf16(wp[128], wp[192]);
            v.z = pack_bf16(wp[256], wp[320]);
            v.w = pack_bf16(wp[384], wp[448]);
            b[c][u] = *(short8*)&v;
        }
}

// ---------------- main kernel: 1024 blocks x 512 thr (8 waves) ----------------
// block = 16 tokens; wave w owns f in [w*8, w*8+8)  (8-way K-split)
// launch_bounds(512,6): VGPR cap ~85 so the 8 B-loads stay in flight under
// the A-gen VALU work (R5's (512,8) forced VGPR=32 -> serialized loads).
__global__ __launch_bounds__(512, 6)
void moe_main(const float* __restrict__ x,   const float* __restrict__ s,
              const float* __restrict__ fw1, const float* __restrict__ fb1,
              const float* __restrict__ fw2, const float* __restrict__ fb2,
              const float* __restrict__ fw3, const float* __restrict__ fb3,
              const float* __restrict__ ew1, const float* __restrict__ eb1,
              const float* __restrict__ ew3, const float* __restrict__ eb3,
              const unsigned short* __restrict__ w3img, int use_ws,
              float* __restrict__ out)
{
    __shared__ __align__(16) float xls[16 * 68];    // x tile [t][f]       4352 B
    __shared__ __align__(16) float wts[16 * 65];    // gates  [t][f]       4160 B
    __shared__ __align__(16) float egs[16 * 64];    // elu(g) [t][h]       4096 B
    __shared__ __align__(16) float ped[4][16 * 68]; // partials (tree)    17408 B

    const int tid = threadIdx.x;
    const int wv = tid >> 6, lane = tid & 63;
    const int tokbase = blockIdx.x * 16;

    // ---- stage x tile (first 256 threads) ----
    if (tid < 256) {
        const int t = tid >> 4, fq = (tid & 15) * 4;
        *(float4*)&xls[t * 68 + fq] =
            *(const float4*)(x + (size_t)(tokbase + t) * 64 + fq);
    }
    __syncthreads();

    // ---- gating: each wave computes softmax gates for its 2 tokens ----
    {
        const int t0w = wv * 2;
        const float* sw = s + (size_t)(tokbase + t0w) * 32;
        float g0, g1;
        g0 = g1 = fb1[lane] + fb2[lane];
        for (int f = 0; f < 64; f += 4) {
            const float4 xa = *(const float4*)&xls[(t0w + 0) * 68 + f];
            const float4 xb = *(const float4*)&xls[(t0w + 1) * 68 + f];
            const float w0 = fw1[(f + 0) * 64 + lane];
            const float w1 = fw1[(f + 1) * 64 + lane];
            const float w2 = fw1[(f + 2) * 64 + lane];
            const float w3v = fw1[(f + 3) * 64 + lane];
            g0 = fmaf(xa.x, w0, fmaf(xa.y, w1, fmaf(xa.z, w2, fmaf(xa.w, w3v, g0))));
            g1 = fmaf(xb.x, w0, fmaf(xb.y, w1, fmaf(xb.z, w2, fmaf(xb.w, w3v, g1))));
        }
        for (int e = 0; e < 32; e += 4) {
            const float4 sa = *(const float4*)(sw + e);
            const float4 sb = *(const float4*)(sw + 32 + e);
            const float w0 = fw2[(e + 0) * 64 + lane];
            const float w1 = fw2[(e + 1) * 64 + lane];
            const float w2 = fw2[(e + 2) * 64 + lane];
            const float w3v = fw2[(e + 3) * 64 + lane];
            g0 = fmaf(sa.x, w0, fmaf(sa.y, w1, fmaf(sa.z, w2, fmaf(sa.w, w3v, g0))));
            g1 = fmaf(sb.x, w0, fmaf(sb.y, w1, fmaf(sb.z, w2, fmaf(sb.w, w3v, g1))));
        }
        // egs rows are wave-private (wave wv touches rows 2wv, 2wv+1 only):
        // in-wave LDS RAW is ordered by lgkmcnt -> no block barrier needed.
        egs[(t0w + 0) * 64 + lane] = eluf(g0);
        egs[(t0w + 1) * 64 + lane] = eluf(g1);

        float lg0 = fb3[lane], lg1 = lg0;
        for (int h = 0; h < 64; h += 4) {
            const float4 e0 = *(const float4*)&egs[(t0w + 0) * 64 + h];
            const float4 e1 = *(const float4*)&egs[(t0w + 1) * 64 + h];
            const float w0 = fw3[(h + 0) * 64 + lane];
            const float w1 = fw3[(h + 1) * 64 + lane];
            const float w2 = fw3[(h + 2) * 64 + lane];
            const float w3v = fw3[(h + 3) * 64 + lane];
            lg0 = fmaf(e0.x, w0, fmaf(e0.y, w1, fmaf(e0.z, w2, fmaf(e0.w, w3v, lg0))));
            lg1 = fmaf(e1.x, w0, fmaf(e1.y, w1, fmaf(e1.z, w2, fmaf(e1.w, w3v, lg1))));
        }
        float mx0 = lg0, mx1 = lg1;
        #pragma unroll
        for (int off = 32; off > 0; off >>= 1) {
            mx0 = fmaxf(mx0, __shfl_xor(mx0, off));
            mx1 = fmaxf(mx1, __shfl_xor(mx1, off));
        }
        const float p0 = __expf(lg0 - mx0), p1 = __expf(lg1 - mx1);
        float s0 = p0, s1 = p1;
        #pragma unroll
        for (int off = 32; off > 0; off >>= 1) {
            s0 += __shfl_xor(s0, off);
            s1 += __shfl_xor(s1, off);
        }
        wts[(t0w + 0) * 65 + lane] = p0 / s0;
        wts[(t0w + 1) * 65 + lane] = p1 / s1;
    }
    __syncthreads();

    // ---- MFMA main loop: wave tile = 16 tok x 64 out, f in [wv*8, wv*8+8) ----
    const int m = tid & 15, quad = (tid >> 4) & 3;
    const int f0 = wv * 8;

    f32x4 acc[4];
    #pragma unroll
    for (int u = 0; u < 4; ++u) acc[u] = (f32x4){0.f, 0.f, 0.f, 0.f};

    if (use_ws) {
        // per-f image pointer for this lane; advance by 512 uint4 per f
        const uint4* bp = (const uint4*)w3img + (size_t)f0 * 512 + lane;
        #pragma unroll
        for (int ff = 0; ff < 8; ++ff) {
            const int f = f0 + ff;
            // 1) issue all 8 B-fragment loads (fly under the A-gen VALU below)
            uint4 b0 = bp[0 * 64];
            uint4 b1 = bp[1 * 64];
            uint4 b2 = bp[2 * 64];
            uint4 b3 = bp[3 * 64];
            uint4 b4 = bp[256 + 0 * 64];
            uint4 b5 = bp[256 + 1 * 64];
            uint4 b6 = bp[256 + 2 * 64];
            uint4 b7 = bp[256 + 3 * 64];
            bp += 512;
            // 2) A-gen (elu + pack) while loads are in flight
            const float xv = xls[m * 68 + f];
            const float wt = wts[m * 65 + f];
            short8 a[2];
            gen_a(ew1, eb1, f, quad, xv, wt, a);
            // 3) consume
            acc[0] = __builtin_amdgcn_mfma_f32_16x16x32_bf16(a[0], *(short8*)&b0, acc[0], 0, 0, 0);
            acc[1] = __builtin_amdgcn_mfma_f32_16x16x32_bf16(a[0], *(short8*)&b1, acc[1], 0, 0, 0);
            acc[2] = __builtin_amdgcn_mfma_f32_16x16x32_bf16(a[0], *(short8*)&b2, acc[2], 0, 0, 0);
            acc[3] = __builtin_amdgcn_mfma_f32_16x16x32_bf16(a[0], *(short8*)&b3, acc[3], 0, 0, 0);
            acc[0] = __builtin_amdgcn_mfma_f32_16x16x32_bf16(a[1], *(short8*)&b4, acc[0], 0, 0, 0);
            acc[1] = __builtin_amdgcn_mfma_f32_16x16x32_bf16(a[1], *(short8*)&b5, acc[1], 0, 0, 0);
            acc[2] = __builtin_amdgcn_mfma_f32_16x16x32_bf16(a[1], *(short8*)&b6, acc[2], 0, 0, 0);
            acc[3] = __builtin_amdgcn_mfma_f32_16x16x32_bf16(a[1], *(short8*)&b7, acc[3], 0, 0, 0);
        }
    } else {
        for (int ff = 0; ff < 8; ++ff) {
            const int f = f0 + ff;
            short8 b[2][4], a[2];
            gen_b_fp32(ew3 + (size_t)f * 4096, quad, m, b);
            gen_a(ew1, eb1, f, quad, xls[m * 68 + f], wts[m * 65 + f], a);
            #pragma unroll
            for (int u = 0; u < 4; ++u) {
                acc[u] = __builtin_amdgcn_mfma_f32_16x16x32_bf16(a[0], b[0][u], acc[u], 0, 0, 0);
                acc[u] = __builtin_amdgcn_mfma_f32_16x16x32_bf16(a[1], b[1][u], acc[u], 0, 0, 0);
            }
        }
    }

    // ---- bias K-chunk (waves 0,1): out += w_t @ eb3 ----
    if (wv < 2) {
        const int e0 = wv * 32 + quad * 8;
        uint4 av;
        av.x = pack_bf16(wts[m * 65 + e0 + 0], wts[m * 65 + e0 + 1]);
        av.y = pack_bf16(wts[m * 65 + e0 + 2], wts[m * 65 + e0 + 3]);
        av.z = pack_bf16(wts[m * 65 + e0 + 4], wts[m * 65 + e0 + 5]);
        av.w = pack_bf16(wts[m * 65 + e0 + 6], wts[m * 65 + e0 + 7]);
        short8 a = *(short8*)&av;
        short8 b[4];
        if (use_ws) {
            const uint4* bq = (const uint4*)(w3img + (size_t)64 * 4096);
            #pragma unroll
            for (int u = 0; u < 4; ++u) {
                uint4 bv = bq[wv * 256 + u * 64 + lane];
                b[u] = *(short8*)&bv;
            }
        } else {
            #pragma unroll
            for (int u = 0; u < 4; ++u) {
                const float* wp = eb3 + (size_t)e0 * 64 + u * 16 + m;
                uint4 bv;
                bv.x = pack_bf16(wp[0],   wp[64]);
                bv.y = pack_bf16(wp[128], wp[192]);
                bv.z = pack_bf16(wp[256], wp[320]);
                bv.w = pack_bf16(wp[384], wp[448]);
                b[u] = *(short8*)&bv;
            }
        }
        #pragma unroll
        for (int u = 0; u < 4; ++u)
            acc[u] = __builtin_amdgcn_mfma_f32_16x16x32_bf16(a, b[u], acc[u], 0, 0, 0);
    }

    // ---- tree reduction over 8 wave-partials (C layout: row=quad*4+r, col=u*16+m) ----
    if (wv >= 4) {
        #pragma unroll
        for (int u = 0; u < 4; ++u)
            #pragma unroll
            for (int r = 0; r < 4; ++r)
                ped[wv - 4][(quad * 4 + r) * 68 + u * 16 + m] = acc[u][r];
    }
    __syncthreads();
    if (wv < 4) {
        #pragma unroll
        for (int u = 0; u < 4; ++u)
            #pragma unroll
            for (int r = 0; r < 4; ++r)
                acc[u][r] += ped[wv][(quad * 4 + r) * 68 + u * 16 + m];
    }
    __syncthreads();
    if (wv == 2 || wv == 3) {
        #pragma unroll
        for (int u = 0; u < 4; ++u)
            #pragma unroll
            for (int r = 0; r < 4; ++r)
                ped[wv - 2][(quad * 4 + r) * 68 + u * 16 + m] = acc[u][r];
    }
    __syncthreads();
    if (wv < 2) {
        #pragma unroll
        for (int u = 0; u < 4; ++u)
            #pragma unroll
            for (int r = 0; r < 4; ++r)
                acc[u][r] += ped[wv][(quad * 4 + r) * 68 + u * 16 + m];
    }
    __syncthreads();
    if (wv == 1) {
        #pragma unroll
        for (int u = 0; u < 4; ++u)
            #pragma unroll
            for (int r = 0; r < 4; ++r)
                ped[0][(quad * 4 + r) * 68 + u * 16 + m] = acc[u][r];
    }
    __syncthreads();
    if (wv == 0) {
        #pragma unroll
        for (int u = 0; u < 4; ++u)
            #pragma unroll
            for (int r = 0; r < 4; ++r) {
                const int idx = (quad * 4 + r) * 68 + u * 16 + m;
                ped[0][idx] += acc[u][r];
            }
    }
    __syncthreads();

    // ---- final store: [t][k] fp32, float4, coalesced ----
    if (tid < 256) {
        const int t = tid >> 4, kq = tid & 15;
        float4 o = *(const float4*)&ped[0][t * 68 + kq * 4];
        *(float4*)(out + (size_t)(tokbase + t) * 64 + kq * 4) = o;
    }
}

extern "C" void kernel_launch(void* const* d_in, const int* in_sizes, int n_in,
                              void* d_out, int out_size, void* d_ws, size_t ws_size,
                              hipStream_t stream) {
    const float* x   = (const float*)d_in[0];
    const float* s   = (const float*)d_in[1];
    const float* fw1 = (const float*)d_in[2];
    const float* fb1 = (const float*)d_in[3];
    const float* fw2 = (const float*)d_in[4];
    const float* fb2 = (const float*)d_in[5];
    const float* fw3 = (const float*)d_in[6];
    const float* fb3 = (const float*)d_in[7];
    const float* ew1 = (const float*)d_in[8];
    const float* eb1 = (const float*)d_in[9];
    const float* ew3 = (const float*)d_in[10];
    const float* eb3 = (const float*)d_in[11];
    float* out = (float*)d_out;

    const size_t ws_need = (size_t)65 * 4096 * sizeof(unsigned short);  // 532,480 B
    const int use_ws = (ws_size >= ws_need) && (((uintptr_t)d_ws & 15) == 0);
    unsigned short* w3img = (unsigned short*)d_ws;

    if (use_ws) prepass<<<dim3(65), dim3(256), 0, stream>>>(ew3, eb3, w3img);
    moe_main<<<dim3(NTOK / 16), dim3(512), 0, stream>>>(
        x, s, fw1, fb1, fw2, fb2, fw3, fb3, ew1, eb1, ew3, eb3,
        w3img, use_ws, out);
}